// Round 1
// baseline (60.728 us; speedup 1.0000x reference)
//
#include <hip/hip_runtime.h>

// Problem constants (from reference): B=32, NY=32, NX=32, D=1024
#define PB 32
#define PNY 32
#define PNX 32
#define PD 1024

// Kernel 1: per-(b, xc) valid prefix length L = sum_y mask[b, y, xc].
// 1024 outputs; consecutive threads -> consecutive xc -> coalesced reads per y.
__global__ __launch_bounds__(256) void upip_lengths_kernel(
    const int* __restrict__ mask, int* __restrict__ Lbuf) {
    int i = blockIdx.x * blockDim.x + threadIdx.x;  // i = b*NX + xc
    if (i >= PB * PNX) return;
    int b  = i / PNX;
    int xc = i % PNX;
    const int* m = mask + (size_t)b * (PNY * PNX) + xc;
    int s = 0;
#pragma unroll
    for (int y = 0; y < PNY; ++y) s += m[(size_t)y * PNX];
    Lbuf[i] = s;
}

// Kernel 2: one block per output row (bp, t), bp = b*NX + xc.
// out[(bp*NY + t)*D + d] = lerp(x[b, lo, xc, :], x[b, hi, xc, :], w)
__global__ __launch_bounds__(256) void upip_upsample_kernel(
    const float* __restrict__ x, const int* __restrict__ Lbuf,
    float* __restrict__ out) {
    const int row = blockIdx.x;        // row = bp*NY + t  (matches out layout)
    const int t   = row & (PNY - 1);
    const int bp  = row >> 5;          // / NY
    const int b   = bp >> 5;           // / NX
    const int xc  = bp & (PNX - 1);

    const int   L  = Lbuf[bp];
    const float Lf = (float)L;

    // PyTorch F.interpolate(linear, align_corners=False) coords, fp32 op-order
    // identical to the reference:
    float src = ((float)t + 0.5f) * (Lf * 0.03125f) - 0.5f;  // *(L/32)
    src = fminf(fmaxf(src, 0.0f), Lf - 1.0f);
    const int   lo = (int)floorf(src);
    const int   hi = min(lo + 1, L - 1);
    const float w  = src - (float)lo;

    // x layout: [B, NY, NX, D] flattened as (b*NY*NX + y*NX + xc)*D
    const size_t base_lo = ((size_t)b * (PNY * PNX) + (size_t)lo * PNX + xc) * PD;
    const size_t base_hi = ((size_t)b * (PNY * PNX) + (size_t)hi * PNX + xc) * PD;
    const size_t obase   = (size_t)row * PD;

    const int d4 = threadIdx.x * 4;  // 256 threads * float4 = 1024 elems

    const float4 vlo = *reinterpret_cast<const float4*>(x + base_lo + d4);
    const float4 vhi = *reinterpret_cast<const float4*>(x + base_hi + d4);

    float4 o;
    o.x = vlo.x * (1.0f - w) + vhi.x * w;
    o.y = vlo.y * (1.0f - w) + vhi.y * w;
    o.z = vlo.z * (1.0f - w) + vhi.z * w;
    o.w = vlo.w * (1.0f - w) + vhi.w * w;

    *reinterpret_cast<float4*>(out + obase + d4) = o;
}

extern "C" void kernel_launch(void* const* d_in, const int* in_sizes, int n_in,
                              void* d_out, int out_size, void* d_ws, size_t ws_size,
                              hipStream_t stream) {
    const float* x    = (const float*)d_in[0];
    const int*   mask = (const int*)d_in[1];
    float*       out  = (float*)d_out;
    int*         Lbuf = (int*)d_ws;  // PB*PNX ints = 4 KiB

    upip_lengths_kernel<<<(PB * PNX + 255) / 256, 256, 0, stream>>>(mask, Lbuf);

    const int nrows = PB * PNX * PNY;  // 32768
    upip_upsample_kernel<<<nrows, 256, 0, stream>>>(x, Lbuf, out);
}

// Round 2
// 56.225 us; speedup vs baseline: 1.0801x; 1.0801x over previous
//
#include <hip/hip_runtime.h>

// Problem constants (from reference): B=32, NY=32, NX=32, D=1024
#define PB 32
#define PNY 32
#define PNX 32
#define PD 1024

// Fused kernel: one block per output row (bp, t), bp = b*NX + xc.
// Each wave computes L = sum_y mask[b, y, xc] via ballot (lanes 0..31),
// then all 256 threads gather lo/hi rows with float4 and lerp.
__global__ __launch_bounds__(256) void upip_fused_kernel(
    const float* __restrict__ x, const int* __restrict__ mask,
    float* __restrict__ out) {
    const int row = blockIdx.x;        // row = bp*NY + t  (matches out layout)
    const int t   = row & (PNY - 1);
    const int bp  = row >> 5;          // / NY
    const int b   = bp >> 5;           // / NX
    const int xc  = bp & (PNX - 1);

    // Per-wave length: lanes 0..31 read mask[b, lane, xc]; popcount of ballot.
    const int lane = threadIdx.x & 63;
    int mv = 0;
    if (lane < PNY)
        mv = mask[(size_t)b * (PNY * PNX) + (size_t)lane * PNX + xc];
    const int   L  = (int)__popcll(__ballot(mv != 0));
    const float Lf = (float)L;

    // PyTorch F.interpolate(linear, align_corners=False), fp32 op-order
    float src = ((float)t + 0.5f) * (Lf * 0.03125f) - 0.5f;  // *(L/32)
    src = fminf(fmaxf(src, 0.0f), Lf - 1.0f);
    const int   lo = (int)floorf(src);
    const int   hi = min(lo + 1, L - 1);
    const float w  = src - (float)lo;

    // x layout: [B, NY, NX, D] flattened as (b*NY*NX + y*NX + xc)*D
    const size_t col_base = ((size_t)b * (PNY * PNX) + xc) * PD;
    const int    d4       = threadIdx.x << 2;  // 256 threads * float4 = 1024

    const float4 vlo = *reinterpret_cast<const float4*>(
        x + col_base + (size_t)lo * (PNX * PD) + d4);
    float4 vhi;
    if (hi != lo) {  // uniform branch; avoids redundant load at the clamp edge
        vhi = *reinterpret_cast<const float4*>(
            x + col_base + (size_t)hi * (PNX * PD) + d4);
    } else {
        vhi = vlo;
    }

    const float iw = 1.0f - w;
    float4 o;
    o.x = vlo.x * iw + vhi.x * w;
    o.y = vlo.y * iw + vhi.y * w;
    o.z = vlo.z * iw + vhi.z * w;
    o.w = vlo.w * iw + vhi.w * w;

    *reinterpret_cast<float4*>(out + (size_t)row * PD + d4) = o;
}

extern "C" void kernel_launch(void* const* d_in, const int* in_sizes, int n_in,
                              void* d_out, int out_size, void* d_ws, size_t ws_size,
                              hipStream_t stream) {
    const float* x    = (const float*)d_in[0];
    const int*   mask = (const int*)d_in[1];
    float*       out  = (float*)d_out;

    const int nrows = PB * PNX * PNY;  // 32768 output rows
    upip_fused_kernel<<<nrows, 256, 0, stream>>>(x, mask, out);
}

// Round 3
// 38.520 us; speedup vs baseline: 1.5765x; 1.4596x over previous
//
#include <hip/hip_runtime.h>

// Problem constants (from reference): B=32, NY=32, NX=32, D=1024
#define PB 32
#define PNY 32
#define PNX 32
#define PD 1024
#define DCHUNK 256                 // floats per block along D (64 lanes * float4)
#define NCHUNK (PD / DCHUNK)       // 4

// One wave (64 threads) per (bp, d-chunk). Walks all 32 output t's for its
// 256-float slice of one (b, xc) column. lo(t) is monotone nondecreasing with
// step <= 1, so a 2-register rolling cache loads each source row exactly once.
__global__ __launch_bounds__(64) void upip_col_kernel(
    const float* __restrict__ x, const int* __restrict__ mask,
    float* __restrict__ out) {
    const int gb    = blockIdx.x;            // gb = bp * NCHUNK + chunk
    const int chunk = gb & (NCHUNK - 1);
    const int bp    = gb >> 2;               // / NCHUNK
    const int b     = bp >> 5;               // / NX
    const int xc    = bp & (PNX - 1);

    // Wave-level length: lanes 0..31 read mask[b, lane, xc]; popcount ballot.
    const int lane = threadIdx.x;            // 0..63
    int mv = 0;
    if (lane < PNY)
        mv = mask[(size_t)b * (PNY * PNX) + (size_t)lane * PNX + xc];
    const int   L  = (int)__popcll(__ballot(mv != 0));
    const float Lf = (float)L;

    // x layout: [B, NY, NX, D]; this thread's 16B slice of the column:
    const size_t row_stride = (size_t)PNX * PD;
    const float* colp = x + ((size_t)b * (PNY * PNX) + xc) * PD
                          + chunk * DCHUNK + lane * 4;
    float*       outp = out + (size_t)bp * PNY * PD + chunk * DCHUNK + lane * 4;

    const float scale = Lf * 0.03125f;       // L / 32, exact in fp32

    int    c0 = -1, c1 = -1;                 // cached row indices for r0, r1
    float4 r0, r1;

    for (int t = 0; t < PNY; ++t) {
        // PyTorch F.interpolate(linear, align_corners=False), fp32 op-order
        float src = ((float)t + 0.5f) * scale - 0.5f;
        src = fminf(fmaxf(src, 0.0f), Lf - 1.0f);
        const int   lo = (int)floorf(src);
        const int   hi = min(lo + 1, L - 1);
        const float w  = src - (float)lo;

        // Rolling 2-row cache; all branches are wave-uniform.
        if (lo == c1)      { r0 = r1; c0 = c1; }
        else if (lo != c0) { r0 = *reinterpret_cast<const float4*>(
                                 colp + (size_t)lo * row_stride); c0 = lo; }
        if (hi == c0)      { r1 = r0; c1 = c0; }
        else if (hi != c1) { r1 = *reinterpret_cast<const float4*>(
                                 colp + (size_t)hi * row_stride); c1 = hi; }

        const float iw = 1.0f - w;
        float4 o;
        o.x = r0.x * iw + r1.x * w;
        o.y = r0.y * iw + r1.y * w;
        o.z = r0.z * iw + r1.z * w;
        o.w = r0.w * iw + r1.w * w;
        *reinterpret_cast<float4*>(outp + (size_t)t * PD) = o;
    }
}

extern "C" void kernel_launch(void* const* d_in, const int* in_sizes, int n_in,
                              void* d_out, int out_size, void* d_ws, size_t ws_size,
                              hipStream_t stream) {
    const float* x    = (const float*)d_in[0];
    const int*   mask = (const int*)d_in[1];
    float*       out  = (float*)d_out;

    const int nblocks = PB * PNX * NCHUNK;   // 4096 single-wave blocks
    upip_col_kernel<<<nblocks, 64, 0, stream>>>(x, mask, out);
}